// Round 5
// baseline (185.770 us; speedup 1.0000x reference)
//
#include <hip/hip_runtime.h>
#include <hip/hip_bf16.h>
#include <math.h>
#include <stdint.h>

// Shapes: B=64, T=256, R=49, H=1024
// out = [c_t (B*T*H fp32)] ++ [alpha (B*T*R fp32)]
// ws  = [cv fp32 3136x49][cg fp32 16384x49][a16 bf16 16384x64 swz]
//       [vT bf16 64x1024x64 swz][wv16 bf16 64x1024][wg16 bf16 64x1024]

typedef __attribute__((ext_vector_type(8))) short bf16x8;
typedef __attribute__((ext_vector_type(4))) short bf16x4;
typedef __attribute__((ext_vector_type(4))) float floatx4;

static __device__ __forceinline__ bf16x8 pack8(float4 a, float4 b) {
    union { __hip_bfloat162 h[4]; bf16x8 v; } u;
    u.h[0] = __float22bfloat162_rn(make_float2(a.x, a.y));
    u.h[1] = __float22bfloat162_rn(make_float2(a.z, a.w));
    u.h[2] = __float22bfloat162_rn(make_float2(b.x, b.y));
    u.h[3] = __float22bfloat162_rn(make_float2(b.z, b.w));
    return u.v;
}

static __device__ __forceinline__ unsigned short f2bf_bits(float f) {
    union { __hip_bfloat16 h; unsigned short u; } c;
    c.h = __float2bfloat16(f);
    return c.u;
}

// Prep: blocks 0..15 -> wv16 (Wv bf16, rows>=49 zeroed); 16..31 -> wg16;
// 32..1055 -> V transpose to vT[b][h][r pad 64] bf16, octet-swizzled.
__global__ __launch_bounds__(256) void prep(const float* __restrict__ V,
                                            const float* __restrict__ Wv,
                                            const float* __restrict__ Wg,
                                            unsigned short* __restrict__ wv16,
                                            unsigned short* __restrict__ wg16,
                                            unsigned short* __restrict__ vT) {
    const int bid = blockIdx.x;
    const int tid = threadIdx.x;

    if (bid < 32) {
        const float* W = (bid < 16) ? Wv : Wg;
        unsigned short* O = (bid < 16) ? wv16 : wg16;
        const int r = (bid & 15) * 4 + (tid >> 6);
        const int kb = (tid & 63) * 16;
        float4 f0, f1, f2, f3;
        if (r < 49) {
            const float* p = W + (size_t)r * 1024 + kb;
            f0 = *(const float4*)(p);
            f1 = *(const float4*)(p + 4);
            f2 = *(const float4*)(p + 8);
            f3 = *(const float4*)(p + 12);
        } else {
            f0 = f1 = f2 = f3 = make_float4(0.f, 0.f, 0.f, 0.f);
        }
        unsigned short* o = O + (size_t)r * 1024 + kb;
        *(bf16x8*)(o) = pack8(f0, f1);
        *(bf16x8*)(o + 8) = pack8(f2, f3);
        return;
    }

    // ---- V transpose: one (b, 64-h slice) per block ----
    __shared__ __align__(16) float Ts[49 * 68];
    const int tb = bid - 32;
    const int b = tb >> 4;
    const int h0 = (tb & 15) * 64;
    for (int i = tid; i < 49 * 16; i += 256) {
        const int r = i >> 4, hq = i & 15;
        *(float4*)(Ts + r * 68 + hq * 4) =
            *(const float4*)(V + ((size_t)b * 49 + r) * 1024 + h0 + hq * 4);
    }
    __syncthreads();
    const int h = tid & 63;
    const int grp = tid >> 6;
    float f[16];
#pragma unroll
    for (int j = 0; j < 16; ++j) {
        const int r = grp * 16 + j;
        f[j] = (r < 49) ? Ts[r * 68 + h] : 0.f;
    }
    const size_t rowbase = ((size_t)b * 1024 + h0 + h) * 64;
#pragma unroll
    for (int o2 = 0; o2 < 2; ++o2) {
        const int o = grp * 2 + o2;
        bf16x8 v = pack8(make_float4(f[o2*8+0], f[o2*8+1], f[o2*8+2], f[o2*8+3]),
                         make_float4(f[o2*8+4], f[o2*8+5], f[o2*8+6], f[o2*8+7]));
        *(bf16x8*)(vT + rowbase + (size_t)((o ^ (h & 7)) * 8)) = v;
    }
}

// C[m][n] = sum_k A[m][k]*W[n][k], K=1024, N=64 (rows>=49 of W are zero).
// One wave per block, m-tile 16, all 64 n. Direct global->fragment loads,
// no LDS, no barriers. Depth-4 register prefetch pipeline, fully unrolled.
// Blocks 0..195: cv (A=V); 196..1219: cg (A=h_t).
__global__ __launch_bounds__(64) void gemm_direct(const float* __restrict__ Av,
                                                  const float* __restrict__ Ag,
                                                  const unsigned short* __restrict__ wv16,
                                                  const unsigned short* __restrict__ wg16,
                                                  float* __restrict__ Cv,
                                                  float* __restrict__ Cg) {
    const int bid = blockIdx.x;
    const int lane = threadIdx.x;
    const int l16 = lane & 15, quad = lane >> 4;

    const float* A; const unsigned short* W; float* C; int m0;
    if (bid < 196) { A = Av;  W = wv16; C = Cv; m0 = bid * 16; }
    else           { A = Ag;  W = wg16; C = Cg; m0 = (bid - 196) * 16; }

    const float* aptr = A + (size_t)(m0 + l16) * 1024 + quad * 8;
    const unsigned short* bptr = W + (size_t)l16 * 1024 + quad * 8;

    floatx4 acc[4] = {};
    float4 ra0[4], ra1[4];
    bf16x8 rb[4][4];

#pragma unroll
    for (int s = 0; s < 4; ++s) {
        ra0[s] = *(const float4*)(aptr + s * 32);
        ra1[s] = *(const float4*)(aptr + s * 32 + 4);
#pragma unroll
        for (int j = 0; j < 4; ++j)
            rb[s][j] = *(const bf16x8*)(bptr + j * 16384 + s * 32);
    }

#pragma unroll
    for (int s = 0; s < 32; ++s) {
        const int slot = s & 3;
        bf16x8 af = pack8(ra0[slot], ra1[slot]);
#pragma unroll
        for (int j = 0; j < 4; ++j)
            acc[j] = __builtin_amdgcn_mfma_f32_16x16x32_bf16(af, rb[slot][j], acc[j], 0, 0, 0);
        if (s < 28) {
            const int k = (s + 4) * 32;
            ra0[slot] = *(const float4*)(aptr + k);
            ra1[slot] = *(const float4*)(aptr + k + 4);
#pragma unroll
            for (int j = 0; j < 4; ++j)
                rb[slot][j] = *(const bf16x8*)(bptr + j * 16384 + k);
        }
    }

    // D layout: col n = j*16 + l16, row m = m0 + quad*4 + r
#pragma unroll
    for (int j = 0; j < 4; ++j) {
        const int n = j * 16 + l16;
        if (n < 49) {
#pragma unroll
            for (int r = 0; r < 4; ++r)
                C[(size_t)(m0 + quad * 4 + r) * 49 + n] = acc[j][r];
        }
    }
}

// z[b,t,r] = sum_k tanh(cv[b,r,k]+cg[b,t,k])*Wh[k]; alpha = softmax_r(z).
__global__ __launch_bounds__(256) void zsoftmax(const float* __restrict__ cv,
                                                const float* __restrict__ cg,
                                                const float* __restrict__ Wh,
                                                float* __restrict__ alpha,
                                                unsigned short* __restrict__ a16) {
    const int b = blockIdx.x >> 4;
    const int t0 = (blockIdx.x & 15) * 16;
    __shared__ __align__(16) float cvl[49 * 52];
    __shared__ __align__(16) float cgl[16 * 52];
    __shared__ __align__(16) float whl[52];

    const int tid = threadIdx.x;
    for (int i = tid; i < 49 * 49; i += 256) {
        int r = i / 49, k = i - r * 49;
        cvl[r * 52 + k] = cv[(size_t)b * 2401 + i];
    }
    for (int i = tid; i < 16 * 49; i += 256) {
        int t = i / 49, k = i - t * 49;
        cgl[t * 52 + k] = cg[((size_t)b * 256 + t0) * 49 + i];
    }
    if (tid < 52) whl[tid] = (tid < 49) ? Wh[tid] : 0.f;
    __syncthreads();

    const int wave = tid >> 6;
    const int lane = tid & 63;
    const float4* cvr = (const float4*)(cvl + lane * 52);
    const float4* wh4 = (const float4*)whl;

    for (int i = 0; i < 4; ++i) {
        const int tl = wave * 4 + i;
        float z = -INFINITY;
        if (lane < 49) {
            const float4* cgr = (const float4*)(cgl + tl * 52);
            float s = 0.f;
#pragma unroll 4
            for (int kk = 0; kk < 12; ++kk) {
                float4 x = cvr[kk], g = cgr[kk], w = wh4[kk];
                float r0 = __builtin_amdgcn_rcpf(__expf(2.f * (x.x + g.x)) + 1.f);
                float r1 = __builtin_amdgcn_rcpf(__expf(2.f * (x.y + g.y)) + 1.f);
                float r2 = __builtin_amdgcn_rcpf(__expf(2.f * (x.z + g.z)) + 1.f);
                float r3 = __builtin_amdgcn_rcpf(__expf(2.f * (x.w + g.w)) + 1.f);
                s = fmaf(1.f - 2.f * r0, w.x, s);
                s = fmaf(1.f - 2.f * r1, w.y, s);
                s = fmaf(1.f - 2.f * r2, w.z, s);
                s = fmaf(1.f - 2.f * r3, w.w, s);
            }
            {
                float x = cvl[lane * 52 + 48] + cgl[tl * 52 + 48];
                float r0 = __builtin_amdgcn_rcpf(__expf(2.f * x) + 1.f);
                s = fmaf(1.f - 2.f * r0, whl[48], s);
            }
            z = s;
        }
        float m = z;
        for (int off = 32; off; off >>= 1) m = fmaxf(m, __shfl_xor(m, off));
        float p = (lane < 49) ? __expf(z - m) : 0.f;
        float sum = p;
        for (int off = 32; off; off >>= 1) sum += __shfl_xor(sum, off);
        const float val = p * __builtin_amdgcn_rcpf(sum);

        const size_t grow = (size_t)b * 256 + t0 + tl;
        if (lane < 49) alpha[grow * 49 + lane] = val;
        const int pos = (((lane >> 3) ^ (tl & 7)) << 3) | (lane & 7);
        a16[grow * 64 + pos] = f2bf_bits(val);
    }
}

// c_t[b,t,h] = sum_r alpha[b,t,r] * V[b,r,h] via bf16 MFMA (K=49 pad 64).
__global__ __launch_bounds__(256) void ct_mfma(const unsigned short* __restrict__ a16,
                                               const unsigned short* __restrict__ vT,
                                               float* __restrict__ C) {
    const int bid = blockIdx.x;
    const int b = bid >> 5;
    const int t0 = ((bid >> 3) & 3) * 64;
    const int h0 = (bid & 7) * 128;

    __shared__ __align__(16) short Al[64 * 64];
    __shared__ __align__(16) short Vl[128 * 64];

    const int tid = threadIdx.x;
    {
        const bf16x8* src = (const bf16x8*)(a16 + ((size_t)b * 256 + t0) * 64);
        bf16x8* dst = (bf16x8*)Al;
#pragma unroll
        for (int p = 0; p < 2; ++p) dst[tid + p * 256] = src[tid + p * 256];
    }
    {
        const bf16x8* src = (const bf16x8*)(vT + ((size_t)b * 1024 + h0) * 64);
        bf16x8* dst = (bf16x8*)Vl;
#pragma unroll
        for (int p = 0; p < 4; ++p) dst[tid + p * 256] = src[tid + p * 256];
    }
    __syncthreads();

    const int wave = tid >> 6, lane = tid & 63;
    const int quad = lane >> 4, l16 = lane & 15;
    const int tb = (wave & 1) * 32;
    const int hb = (wave >> 1) * 64;

    floatx4 acc[2][4] = {};
#pragma unroll
    for (int kc = 0; kc < 2; ++kc) {
        bf16x8 af[2];
#pragma unroll
        for (int ms = 0; ms < 2; ++ms) {
            const int row = tb + ms * 16 + l16;
            af[ms] = *(const bf16x8*)(Al + row * 64 + (((kc << 2) + quad) ^ (row & 7)) * 8);
        }
#pragma unroll
        for (int ns = 0; ns < 4; ++ns) {
            const int row = hb + ns * 16 + l16;
            bf16x8 bf = *(const bf16x8*)(Vl + row * 64 + (((kc << 2) + quad) ^ (row & 7)) * 8);
#pragma unroll
            for (int ms = 0; ms < 2; ++ms)
                acc[ms][ns] = __builtin_amdgcn_mfma_f32_16x16x32_bf16(af[ms], bf, acc[ms][ns], 0, 0, 0);
        }
    }

#pragma unroll
    for (int ms = 0; ms < 2; ++ms) {
        const int t = t0 + tb + ms * 16 + quad * 4;
#pragma unroll
        for (int ns = 0; ns < 4; ++ns) {
            const int h = h0 + hb + ns * 16 + l16;
#pragma unroll
            for (int r = 0; r < 4; ++r)
                C[((size_t)b * 256 + t + r) * 1024 + h] = acc[ms][ns][r];
        }
    }
}

extern "C" void kernel_launch(void* const* d_in, const int* in_sizes, int n_in,
                              void* d_out, int out_size, void* d_ws, size_t ws_size,
                              hipStream_t stream) {
    const float* V   = (const float*)d_in[0];
    const float* h_t = (const float*)d_in[1];
    const float* Wv  = (const float*)d_in[2];
    const float* Wg  = (const float*)d_in[3];
    const float* Wh  = (const float*)d_in[4];

    float* c_t   = (float*)d_out;
    float* alpha = (float*)d_out + 16777216;

    float* cv = (float*)d_ws;                                         // 153664 f
    float* cg = cv + 153664;                                          // 802816 f
    unsigned short* a16  = (unsigned short*)((char*)d_ws + 3825920);  // 16384*64
    unsigned short* vT   = a16 + 16384 * 64;                          // 64*1024*64
    unsigned short* wv16 = vT + (size_t)64 * 1024 * 64;               // 64*1024
    unsigned short* wg16 = wv16 + 64 * 1024;                          // 64*1024

    prep<<<32 + 1024, 256, 0, stream>>>(V, Wv, Wg, wv16, wg16, vT);
    gemm_direct<<<196 + 1024, 64, 0, stream>>>(V, h_t, wv16, wg16, cv, cg);
    zsoftmax<<<1024, 256, 0, stream>>>(cv, cg, Wh, alpha, a16);
    ct_mfma<<<2048, 256, 0, stream>>>(a16, vT, c_t);
}